// Round 12
// baseline (376.559 us; speedup 1.0000x reference)
//
#include <hip/hip_runtime.h>

#define D 128
#define G_NUM 512

typedef unsigned short u16;
typedef unsigned int u32;
typedef __attribute__((ext_vector_type(8))) short bf16x8;
typedef __attribute__((ext_vector_type(4))) float f32x4;

__device__ __forceinline__ float bf2f(u16 u) { return __uint_as_float(((u32)u) << 16); }
__device__ __forceinline__ u16 f2bf_rne(float f) {
    u32 u = __float_as_uint(f);
    return (u16)((u + 0x7FFFu + ((u >> 16) & 1u)) >> 16);
}
// packed u32 = (hi<<16)|lo, value ~= f to ~2^-17 rel
__device__ __forceinline__ u32 packf(float v) {
    u16 h = f2bf_rne(v);
    u16 l = f2bf_rne(v - bf2f(h));
    return ((u32)h << 16) | l;
}
__device__ __forceinline__ float pk_hi(u32 u) { return __uint_as_float(u & 0xFFFF0000u); }
__device__ __forceinline__ float pk_lo(u32 u) { return __uint_as_float(u << 16); }

// 8 packed u32 -> hi/lo bf16x8 fragments
__device__ __forceinline__ void unpack8(const u32* w, bf16x8& hi, bf16x8& lo) {
    union { u32 u[4]; bf16x8 v; } H, L;
#pragma unroll
    for (int p = 0; p < 4; p++) {
        u32 a = w[2 * p], b = w[2 * p + 1];
        H.u[p] = (b & 0xFFFF0000u) | (a >> 16);
        L.u[p] = (b << 16) | (a & 0xFFFFu);
    }
    hi = H.v;
    lo = L.v;
}

// ---------------- fused prep: x->packed | deg histogram | weight pack | boundary ----------------
__global__ void prep_kernel(const float* __restrict__ x, u32* __restrict__ xp,
                            const float* __restrict__ w0, const float* __restrict__ w1,
                            const float* __restrict__ w2, const float* __restrict__ w3,
                            u16* __restrict__ wp,
                            const int* __restrict__ batch, int* __restrict__ gstart,
                            const int* __restrict__ tgt, int* __restrict__ deg,
                            int n4, int E, int N, int NBX, int NBE) {
    int b = blockIdx.x, t = threadIdx.x;
    if (b < NBX) {  // x -> packed bf16 hi|lo
        int i = b * 256 + t;
        if (i >= n4) return;
        float4 v = ((const float4*)x)[i];
        uint4 o;
        o.x = packf(v.x);
        o.y = packf(v.y);
        o.z = packf(v.z);
        o.w = packf(v.w);
        ((uint4*)xp)[i] = o;
    } else if (b < NBX + NBE) {  // in-degree histogram
        int e = (b - NBX) * 256 + t;
        if (e < E) atomicAdd(&deg[tgt[e]], 1);
    } else if (b < NBX + NBE + 32) {  // pack weights into MFMA B-fragment order, hi/lo
        int id = (b - NBX - NBE) * 256 + t;
        int g = id & 3, c = (id >> 2) & 127, kt = (id >> 9) & 3, mat = id >> 11;
        const float* W = (mat == 0) ? w0 : (mat == 1) ? w1 : (mat == 2) ? w2 : w3;
        u16* dh = wp + mat * 32768 + ((size_t)(kt * 128 + c) * 4 + g) * 8;
        u16* dl = dh + 16384;
#pragma unroll
        for (int j = 0; j < 8; j++) {
            float v = W[(size_t)(kt * 32 + g * 8 + j) * D + c];
            u16 h = f2bf_rne(v);
            dh[j] = h;
            dl[j] = f2bf_rne(v - bf2f(h));
        }
    } else {  // graph boundaries from sorted batch
        int i = (b - NBX - NBE - 32) * 256 + t;
        if (i >= N) return;
        int bb = batch[i];
        int bp = (i == 0) ? -1 : batch[i - 1];
        for (int g = bp + 1; g <= bb; g++) gstart[g] = i;
        if (i == N - 1)
            for (int g = bb + 1; g <= G_NUM; g++) gstart[g] = N;
    }
}

// ---------------- single-pass exclusive scan (decoupled lookback, ticket-ordered) ----------------
// Replaces scan1+scan2+scan3. All cross-block state via device-scope atomics (XCD-safe).
// Outputs: row_start (exclusive prefix), rdeg, deg reset to 0 (fill cursor).
__global__ __launch_bounds__(256) void scan_kernel(
    int* __restrict__ deg, int* __restrict__ row_start, float* __restrict__ rdeg,
    int* __restrict__ ticket, int* __restrict__ bflag, int* __restrict__ bstate,
    int N, int E) {
    __shared__ int s[256];
    __shared__ int sblk, sprev;
    int t = threadIdx.x;
    if (t == 0) sblk = atomicAdd(ticket, 1);  // dispatch-ordered block id -> deadlock-free spin
    __syncthreads();
    int b = sblk;
    int i = b * 256 + t;
    int v = (i < N) ? deg[i] : 0;
    s[t] = v;
    __syncthreads();
    for (int off = 1; off < 256; off <<= 1) {
        int add = (t >= off) ? s[t - off] : 0;
        __syncthreads();
        s[t] += add;
        __syncthreads();
    }
    int incl = s[t];
    int total = s[255];
    if (t == 0) {
        atomicExch(&bstate[2 * b], total);  // publish aggregate
        __threadfence();
        atomicExch(&bflag[b], 1);
        int excl = 0;
        for (int p = b - 1; p >= 0; --p) {  // lookback
            int f;
            do { f = atomicAdd(&bflag[p], 0); } while (f == 0);
            if (f == 2) { excl += atomicAdd(&bstate[2 * p + 1], 0); break; }
            excl += atomicAdd(&bstate[2 * p], 0);
        }
        sprev = excl;
        atomicExch(&bstate[2 * b + 1], excl + total);  // publish inclusive prefix
        __threadfence();
        atomicExch(&bflag[b], 2);
    }
    __syncthreads();
    if (i < N) {
        row_start[i] = sprev + incl - v;
        rdeg[i] = 1.0f / fmaxf((float)v, 1.0f);
        deg[i] = 0;  // becomes fill cursor
    }
    if (b == 0 && t == 0) row_start[N] = E;
}

__global__ void fill_kernel(const int* __restrict__ src, const int* __restrict__ tgt,
                            const int* __restrict__ row_start, int* __restrict__ cursor,
                            int* __restrict__ col_idx, int E) {
    int e = blockIdx.x * blockDim.x + threadIdx.x;
    if (e >= E) return;
    int t = tgt[e];
    int pos = row_start[t] + atomicAdd(&cursor[t], 1);
    col_idx[pos] = src[e];
}

// ---------------- fused SAGE layer: gather(mean) + MFMA GEMM ----------------
// 512 threads = 8 waves; VGPR=64 -> 4 blocks/CU; grid 1024 for full occupancy.
// Per 16-row tile (grid-stride): gather 16 nodes x 32 lanes -> LDS (packed, stride 132),
// then wave w computes cols [w*16,w*16+16) with register-resident B; split-bf16 3 terms/operand.
// LAYER 0: relu, write packed u32 h1p.  LAYER 1: write f32 h2.
template <int LAYER>
__global__ __launch_bounds__(512, 4) void sage_fused_kernel(
    const int* __restrict__ row_start, const int* __restrict__ col_idx,
    const float* __restrict__ rdeg, const u32* __restrict__ feat_pk,
    const u16* __restrict__ Wnh, const u16* __restrict__ Wnl,
    const u16* __restrict__ Wrh, const u16* __restrict__ Wrl,
    const float* __restrict__ bias, u32* __restrict__ out_pk,
    float* __restrict__ out_f32, int N, int NT) {
    __shared__ u32 agg[16 * 132];  // packed bf16 hi|lo, stride 132 u32 (bank-spread)

    int tid = threadIdx.x;
    int lane = tid & 63;
    int wave = tid >> 6;  // = ct (16-col slice)
    int r = lane & 15, g = lane >> 4;

    // ---- preload B fragments (1 ct x 4 kt x {Wn,Wr} x {hi,lo} = 16 bf16x8 = 64 VGPR) ----
    bf16x8 Bn[4][2], Br[4][2];
#pragma unroll
    for (int kt = 0; kt < 4; kt++) {
        size_t wo = ((size_t)(kt * 128 + r) * 4 + g) * 8 + (size_t)wave * 512;
        Bn[kt][0] = *(const bf16x8*)(Wnh + wo);
        Bn[kt][1] = *(const bf16x8*)(Wnl + wo);
        Br[kt][0] = *(const bf16x8*)(Wrh + wo);
        Br[kt][1] = *(const bf16x8*)(Wrl + wo);
    }
    float bv = bias[wave * 16 + r];

    int nl = tid >> 5;  // node-local 0..15
    int q = tid & 31;   // feature quad 0..31

    for (int rt = blockIdx.x; rt < NT; rt += gridDim.x) {
        // ---------- gather phase ----------
        int node = rt * 16 + nl;
        float ax = 0.f, ay = 0.f, az = 0.f, aw = 0.f;
        if (node < N) {
            int beg = row_start[node], end = row_start[node + 1];
            int i = beg;
            for (; i + 4 <= end; i += 4) {
                int s0 = col_idx[i], s1 = col_idx[i + 1], s2 = col_idx[i + 2], s3 = col_idx[i + 3];
                uint4 v0 = ((const uint4*)feat_pk)[(size_t)s0 * 32 + q];
                uint4 v1 = ((const uint4*)feat_pk)[(size_t)s1 * 32 + q];
                uint4 v2 = ((const uint4*)feat_pk)[(size_t)s2 * 32 + q];
                uint4 v3 = ((const uint4*)feat_pk)[(size_t)s3 * 32 + q];
                ax += (pk_hi(v0.x) + pk_lo(v0.x)) + (pk_hi(v1.x) + pk_lo(v1.x)) +
                      (pk_hi(v2.x) + pk_lo(v2.x)) + (pk_hi(v3.x) + pk_lo(v3.x));
                ay += (pk_hi(v0.y) + pk_lo(v0.y)) + (pk_hi(v1.y) + pk_lo(v1.y)) +
                      (pk_hi(v2.y) + pk_lo(v2.y)) + (pk_hi(v3.y) + pk_lo(v3.y));
                az += (pk_hi(v0.z) + pk_lo(v0.z)) + (pk_hi(v1.z) + pk_lo(v1.z)) +
                      (pk_hi(v2.z) + pk_lo(v2.z)) + (pk_hi(v3.z) + pk_lo(v3.z));
                aw += (pk_hi(v0.w) + pk_lo(v0.w)) + (pk_hi(v1.w) + pk_lo(v1.w)) +
                      (pk_hi(v2.w) + pk_lo(v2.w)) + (pk_hi(v3.w) + pk_lo(v3.w));
            }
            for (; i < end; i++) {
                int s = col_idx[i];
                uint4 v = ((const uint4*)feat_pk)[(size_t)s * 32 + q];
                ax += pk_hi(v.x) + pk_lo(v.x);
                ay += pk_hi(v.y) + pk_lo(v.y);
                az += pk_hi(v.z) + pk_lo(v.z);
                aw += pk_hi(v.w) + pk_lo(v.w);
            }
            float rd = rdeg[node];
            ax *= rd; ay *= rd; az *= rd; aw *= rd;
        }
        uint4 pk4;
        pk4.x = packf(ax);
        pk4.y = packf(ay);
        pk4.z = packf(az);
        pk4.w = packf(aw);
        *(uint4*)&agg[nl * 132 + q * 4] = pk4;
        __syncthreads();

        // ---------- mfma phase ----------
        int grow = min(rt * 16 + r, N - 1);
        const u32* xrow = feat_pk + (size_t)grow * D;
        f32x4 acc = (f32x4){0.f, 0.f, 0.f, 0.f};
#pragma unroll
        for (int kt = 0; kt < 4; kt++) {
            u32 awb[8];
            *(uint4*)&awb[0] = *(const uint4*)&agg[r * 132 + kt * 32 + g * 8];
            *(uint4*)&awb[4] = *(const uint4*)&agg[r * 132 + kt * 32 + g * 8 + 4];
            bf16x8 ah, al;
            unpack8(awb, ah, al);
            u32 xwb[8];
            *(uint4*)&xwb[0] = *(const uint4*)(xrow + kt * 32 + g * 8);
            *(uint4*)&xwb[4] = *(const uint4*)(xrow + kt * 32 + g * 8 + 4);
            bf16x8 xh, xl;
            unpack8(xwb, xh, xl);
            acc = __builtin_amdgcn_mfma_f32_16x16x32_bf16(ah, Bn[kt][0], acc, 0, 0, 0);
            acc = __builtin_amdgcn_mfma_f32_16x16x32_bf16(al, Bn[kt][0], acc, 0, 0, 0);
            acc = __builtin_amdgcn_mfma_f32_16x16x32_bf16(ah, Bn[kt][1], acc, 0, 0, 0);
            acc = __builtin_amdgcn_mfma_f32_16x16x32_bf16(xh, Br[kt][0], acc, 0, 0, 0);
            acc = __builtin_amdgcn_mfma_f32_16x16x32_bf16(xl, Br[kt][0], acc, 0, 0, 0);
            acc = __builtin_amdgcn_mfma_f32_16x16x32_bf16(xh, Br[kt][1], acc, 0, 0, 0);
        }
#pragma unroll
        for (int reg = 0; reg < 4; reg++) {
            int row = rt * 16 + g * 4 + reg;  // C/D: col=lane&15, row=(lane>>4)*4+reg
            if (row >= N) continue;
            float v = acc[reg] + bv;
            if (LAYER == 0) {
                v = fmaxf(v, 0.f);
                out_pk[(size_t)row * D + wave * 16 + r] = packf(v);
            } else {
                out_f32[(size_t)row * D + wave * 16 + r] = v;
            }
        }
        __syncthreads();
    }
}

// ---------------- per-graph mean pool + FC (512 threads, 16 rows in flight, float4) ----------------
__global__ __launch_bounds__(512) void pool_fc_kernel(
    const float* __restrict__ h2, const int* __restrict__ gstart,
    const float* __restrict__ fcw, const float* __restrict__ fcb, float* __restrict__ out) {
    __shared__ float red[16][132];
    int g = blockIdx.x, t = threadIdx.x;
    int s = gstart[g], e = gstart[g + 1];
    int rr = t >> 5, c4 = t & 31;
    float4 acc = {0.f, 0.f, 0.f, 0.f};
    for (int r = s + rr; r < e; r += 16) {
        float4 v = ((const float4*)(h2 + (size_t)r * D))[c4];
        acc.x += v.x; acc.y += v.y; acc.z += v.z; acc.w += v.w;
    }
    *(float4*)&red[rr][c4 * 4] = acc;
    __syncthreads();
#pragma unroll
    for (int off = 8; off >= 1; off >>= 1) {
        if (rr < off) {
            float4 a = *(float4*)&red[rr][c4 * 4];
            float4 b = *(float4*)&red[rr + off][c4 * 4];
            a.x += b.x; a.y += b.y; a.z += b.z; a.w += b.w;
            *(float4*)&red[rr][c4 * 4] = a;
        }
        __syncthreads();
    }
    if (t < 10) {
        float rc = 1.0f / fmaxf((float)(e - s), 1.0f);
        float o = fcb[t];
#pragma unroll
        for (int k = 0; k < D; k++) o += red[0][k] * rc * fcw[k * 10 + t];
        out[g * 10 + t] = o;
    }
}

extern "C" void kernel_launch(void* const* d_in, const int* in_sizes, int n_in,
                              void* d_out, int out_size, void* d_ws, size_t ws_size,
                              hipStream_t stream) {
    const float* x   = (const float*)d_in[0];
    const int*   ei  = (const int*)d_in[1];
    const int* batch = (const int*)d_in[2];
    const float* w1n = (const float*)d_in[3];
    const float* b1  = (const float*)d_in[4];
    const float* w1r = (const float*)d_in[5];
    const float* w2n = (const float*)d_in[6];
    const float* b2  = (const float*)d_in[7];
    const float* w2r = (const float*)d_in[8];
    const float* fcw = (const float*)d_in[9];
    const float* fcb = (const float*)d_in[10];
    float* out = (float*)d_out;

    int N = in_sizes[0] / D;
    int E = in_sizes[1] / 2;
    const int* src = ei;
    const int* tgt = ei + E;
    int NB = (N + 255) / 256;

    // ---- workspace layout (256B-aligned regions) ----
    auto au = [](size_t v) { return (v + 255) & ~(size_t)255; };
    char* p = (char*)d_ws;
    int*   deg       = (int*)p;    p += au((size_t)N * 4);
    int*   ticket    = (int*)p;    p += au(4);
    int*   bflag     = (int*)p;    p += au((size_t)NB * 4);
    int*   bstate    = (int*)p;    p += au((size_t)2 * NB * 4);
    int*   row_start = (int*)p;    p += au((size_t)(N + 1) * 4);
    int*   col_idx   = (int*)p;    p += au((size_t)E * 4);
    float* rdeg      = (float*)p;  p += au((size_t)N * 4);
    int*   gstart    = (int*)p;    p += au((size_t)(G_NUM + 1) * 4);
    u16*   wp        = (u16*)p;    p += au((size_t)8 * 16384 * 2);
    u32*   xp        = (u32*)p;    p += au((size_t)N * D * 4);  // packed bf16 hi|lo of x
    u32*   h1p       = (u32*)p;    p += au((size_t)N * D * 4);  // packed h1 (post-relu)
    float* h2        = (float*)xp;  // alias: xp dead after fused<0>

    // one memset covers deg | ticket | bflag (contiguous prefix incl. alignment pads)
    size_t zbytes = (size_t)((char*)(bflag + NB) - (char*)deg);
    hipMemsetAsync(deg, 0, zbytes, stream);

    // ---- fused prep: pack-x | deg | pack-w | boundary ----
    int n4 = N * 32;
    int NBX = (n4 + 255) / 256;
    int NBE = (E + 255) / 256;
    prep_kernel<<<NBX + NBE + 32 + NB, 256, 0, stream>>>(
        x, xp, w1n, w1r, w2n, w2r, wp, batch, gstart, tgt, deg, n4, E, N, NBX, NBE);

    // ---- CSR build: single-pass scan + fill ----
    scan_kernel<<<NB, 256, 0, stream>>>(deg, row_start, rdeg, ticket, bflag, bstate, N, E);
    fill_kernel<<<NBE, 256, 0, stream>>>(src, tgt, row_start, deg, col_idx, E);

    int NT = (N + 15) / 16;
    int grid = NT < 1024 ? NT : 1024;

    // ---- layer 1 (gather + GEMM fused) ----
    sage_fused_kernel<0><<<grid, 512, 0, stream>>>(
        row_start, col_idx, rdeg, xp,
        wp + 0 * 32768, wp + 0 * 32768 + 16384,
        wp + 1 * 32768, wp + 1 * 32768 + 16384,
        b1, h1p, nullptr, N, NT);

    // ---- layer 2 (gather + GEMM fused) ----
    sage_fused_kernel<1><<<grid, 512, 0, stream>>>(
        row_start, col_idx, rdeg, h1p,
        wp + 2 * 32768, wp + 2 * 32768 + 16384,
        wp + 3 * 32768, wp + 3 * 32768 + 16384,
        b2, nullptr, h2, N, NT);

    // ---- pool + FC ----
    pool_fc_kernel<<<G_NUM, 512, 0, stream>>>(h2, gstart, fcw, fcb, out);
}